// Round 2
// baseline (222.153 us; speedup 1.0000x reference)
//
#include <hip/hip_runtime.h>
#include <hip/hip_bf16.h>
#include <stdint.h>

#define D_MODEL 1024
#define N_HEADS 16
#define HEAD_DIM 64
#define KV_HEADS 4
#define BATCH 2
#define SEQ 2048
#define MROWS (BATCH * SEQ)      // 4096
#define NQKV 1536                // 1024 Q | 256 K | 256 V
#define QKV_K_OFF 1024
#define QKV_V_OFF 1280

typedef __attribute__((ext_vector_type(8))) short bf16x8;
typedef __attribute__((ext_vector_type(4))) short short4v;
typedef __attribute__((ext_vector_type(4))) float f32x4;

// round-to-nearest-even f32 -> bf16 (bit trick)
__device__ __forceinline__ short f2bf(float f) {
    union { float f; unsigned u; } c; c.f = f;
    unsigned u = c.u + 0x7fffu + ((c.u >> 16) & 1u);
    return (short)(u >> 16);
}

// ---------------------------------------------------------------------------
// fp32 -> bf16 elementwise (x conversion), vectorized float4 -> 4x bf16
// ---------------------------------------------------------------------------
__global__ __launch_bounds__(256) void convert_bf16_kernel(
    const float* __restrict__ in, short* __restrict__ out, int n4)
{
    int i = blockIdx.x * 256 + threadIdx.x;
    if (i < n4) {
        float4 v = ((const float4*)in)[i];
        short4v o;
        o.x = f2bf(v.x); o.y = f2bf(v.y); o.z = f2bf(v.z); o.w = f2bf(v.w);
        ((short4v*)out)[i] = o;
    }
}

// ---------------------------------------------------------------------------
// W [1024][N] fp32 -> W^T [N][1024] bf16 (row stride fixed 1024 = K)
// 64x64 tiles via LDS.
// ---------------------------------------------------------------------------
__global__ __launch_bounds__(256) void transpose_w_kernel(
    const float* __restrict__ in, int N, short* __restrict__ out)
{
    __shared__ short Ts[64][68];          // [n][k], pad 68 keeps 8B alignment
    const int n0 = blockIdx.x * 64, k0 = blockIdx.y * 64;
    const int t = threadIdx.x;
    const int r = t >> 4, c4 = (t & 15) * 4;
    #pragma unroll
    for (int i = 0; i < 4; ++i) {
        int k = r + i * 16;
        float4 v = *(const float4*)(in + (size_t)(k0 + k) * N + n0 + c4);
        Ts[c4 + 0][k] = f2bf(v.x);
        Ts[c4 + 1][k] = f2bf(v.y);
        Ts[c4 + 2][k] = f2bf(v.z);
        Ts[c4 + 3][k] = f2bf(v.w);
    }
    __syncthreads();
    #pragma unroll
    for (int i = 0; i < 4; ++i) {
        int n = r + i * 16;
        short4v o = *(short4v*)&Ts[n][c4];
        *(short4v*)(out + (size_t)(n0 + n) * 1024 + k0 + c4) = o;
    }
}

// ---------------------------------------------------------------------------
// concat bq|bk|bv -> bcat[1536]
// ---------------------------------------------------------------------------
__global__ __launch_bounds__(256) void bias_concat_kernel(
    const float* __restrict__ bq, const float* __restrict__ bk,
    const float* __restrict__ bv, float* __restrict__ bcat)
{
    int n = blockIdx.x * 256 + threadIdx.x;
    if (n < NQKV)
        bcat[n] = n < 1024 ? bq[n] : (n < 1280 ? bk[n - 1024] : bv[n - 1280]);
}

// ---------------------------------------------------------------------------
// bf16 MFMA GEMM: C[M,N] = A[M,1024] @ Bt[N,1024]^T + bias[N]
// 128x128 tile, BK=64, 256 thr (4 waves, 2x2 wave grid, 64x64 out each).
// LDS slot-swizzle (^ row&7) for conflict-free ds_read_b128 fragment reads.
// Global loads of tile k+1 issued before barrier (latency hidden under MFMA).
// ---------------------------------------------------------------------------
template <bool BF16_OUT>
__global__ __launch_bounds__(256) void gemm_kernel(
    const short* __restrict__ A, const short* __restrict__ Bt,
    const float* __restrict__ bias, void* __restrict__ Cv, int N)
{
    __shared__ short As[128 * 64];
    __shared__ short Bs[128 * 64];
    const int t = threadIdx.x;
    const int l = t & 63;
    const int w = t >> 6;
    const int bm = blockIdx.y * 128, bn = blockIdx.x * 128;
    const int wr = (w >> 1) * 64, wc = (w & 1) * 64;
    const int lr = l & 15, lg = l >> 4;

    f32x4 acc[4][4] = {};
    bf16x8 ra[4], rb[4];

    #pragma unroll
    for (int i = 0; i < 4; ++i) {
        int u = t + 256 * i, row = u >> 3, s = u & 7;
        ra[i] = *(const bf16x8*)(A  + (size_t)(bm + row) * 1024 + s * 8);
        rb[i] = *(const bf16x8*)(Bt + (size_t)(bn + row) * 1024 + s * 8);
    }

    for (int k0 = 0; k0 < 1024; k0 += 64) {
        __syncthreads();
        #pragma unroll
        for (int i = 0; i < 4; ++i) {
            int u = t + 256 * i, row = u >> 3, s = u & 7;
            int sd = s ^ (row & 7);
            *(bf16x8*)(&As[row * 64 + sd * 8]) = ra[i];
            *(bf16x8*)(&Bs[row * 64 + sd * 8]) = rb[i];
        }
        if (k0 + 64 < 1024) {
            #pragma unroll
            for (int i = 0; i < 4; ++i) {
                int u = t + 256 * i, row = u >> 3, s = u & 7;
                ra[i] = *(const bf16x8*)(A  + (size_t)(bm + row) * 1024 + k0 + 64 + s * 8);
                rb[i] = *(const bf16x8*)(Bt + (size_t)(bn + row) * 1024 + k0 + 64 + s * 8);
            }
        }
        __syncthreads();
        #pragma unroll
        for (int tt = 0; tt < 2; ++tt) {
            bf16x8 af[4], bfr[4];
            #pragma unroll
            for (int mi = 0; mi < 4; ++mi) {
                int m = wr + mi * 16 + lr;
                af[mi]  = *(const bf16x8*)(&As[m * 64 + ((tt * 4 + lg) ^ (m & 7)) * 8]);
                int n = wc + mi * 16 + lr;
                bfr[mi] = *(const bf16x8*)(&Bs[n * 64 + ((tt * 4 + lg) ^ (n & 7)) * 8]);
            }
            #pragma unroll
            for (int mi = 0; mi < 4; ++mi)
                #pragma unroll
                for (int ni = 0; ni < 4; ++ni)
                    acc[mi][ni] = __builtin_amdgcn_mfma_f32_16x16x32_bf16(
                        af[mi], bfr[ni], acc[mi][ni], 0, 0, 0);
        }
    }

    #pragma unroll
    for (int ni = 0; ni < 4; ++ni) {
        int n = bn + wc + ni * 16 + lr;
        float bv = bias[n];
        #pragma unroll
        for (int mi = 0; mi < 4; ++mi) {
            #pragma unroll
            for (int r = 0; r < 4; ++r) {
                int m = bm + wr + mi * 16 + lg * 4 + r;
                float v = acc[mi][ni][r] + bv;
                if constexpr (BF16_OUT)
                    ((short*)Cv)[(size_t)m * N + n] = f2bf(v);
                else
                    ((float*)Cv)[(size_t)m * N + n] = v;
            }
        }
    }
}

// ---------------------------------------------------------------------------
// Flash causal GQA attention, bf16 MFMA.
// QKV: [4096][1536] bf16 (Q | K | V).  Aout: [4096][1024] bf16.
// Block: 256 thr (4 waves); processes TWO paired q-tiles (qb, 31-qb) so every
// block does exactly 33 kv-tile iterations (causal load balance).
// Per wave: 16 q-rows. Online softmax fully wave-parallel (16-lane shfl).
// LDS: Qs/Ks [row][64] swizzled; Vt = V^T [d][64k] swizzled (transposed at
// staging: per-instruction writes land in one 128B row -> conflict-free).
// ---------------------------------------------------------------------------
__global__ __launch_bounds__(256) void attn_kernel(
    const short* __restrict__ QKV, short* __restrict__ Aout)
{
    __shared__ short Qs[64 * 64];
    __shared__ short Ks[64 * 64];
    __shared__ short Vt[64 * 64];
    __shared__ short Ps[4 * 16 * 64];     // per-wave private P tiles

    const int t = threadIdx.x, l = t & 63, w = t >> 6;
    const int h = blockIdx.y, b = blockIdx.z;
    const int kvh = h >> 2;               // jnp.repeat: h // N_GROUPS
    const int lr = l & 15, lg = l >> 4;
    const float SCL = 0.125f * 1.44269504f;   // 1/sqrt(64) * log2(e)

    const size_t baseQ = (size_t)(b * SEQ) * NQKV + h * 64;
    const size_t baseK = (size_t)(b * SEQ) * NQKV + QKV_K_OFF + kvh * 64;
    const size_t baseV = (size_t)(b * SEQ) * NQKV + QKV_V_OFF + kvh * 64;

    for (int pi = 0; pi < 2; ++pi) {
        const int qb = pi ? (31 - (int)blockIdx.x) : (int)blockIdx.x;
        const int q0 = qb * 64;
        __syncthreads();   // prev pair's reads of Qs/Ks/Vt complete

        // ---- stage Q tile (swizzled) ----
        #pragma unroll
        for (int i = 0; i < 2; ++i) {
            int u = t + 256 * i, row = u >> 3, s = u & 7;
            bf16x8 v = *(const bf16x8*)(QKV + baseQ + (size_t)(q0 + row) * NQKV + s * 8);
            *(bf16x8*)(&Qs[row * 64 + (s ^ (row & 7)) * 8]) = v;
        }
        // ---- prefetch K,V tile kb=0 ----
        bf16x8 rk[2], rv[2];
        #pragma unroll
        for (int i = 0; i < 2; ++i) {
            int u = t + 256 * i, row = u >> 3, s = u & 7;
            rk[i] = *(const bf16x8*)(QKV + baseK + (size_t)row * NQKV + s * 8);
        }
        #pragma unroll
        for (int c = 0; c < 2; ++c) {
            int d0 = (w * 2 + c) * 8;
            rv[c] = *(const bf16x8*)(QKV + baseV + (size_t)l * NQKV + d0);
        }
        __syncthreads();

        // ---- Q fragments (held in regs for whole pair) ----
        bf16x8 qf[2];
        #pragma unroll
        for (int tt = 0; tt < 2; ++tt) {
            int q = w * 16 + lr;
            qf[tt] = *(const bf16x8*)(&Qs[q * 64 + ((tt * 4 + lg) ^ (q & 7)) * 8]);
        }

        float m_i[4], l_i[4];
        f32x4 o[4];
        #pragma unroll
        for (int r = 0; r < 4; ++r) { m_i[r] = -INFINITY; l_i[r] = 0.f; }
        #pragma unroll
        for (int ni = 0; ni < 4; ++ni) o[ni] = (f32x4){0.f, 0.f, 0.f, 0.f};

        for (int kb = 0; kb <= qb; ++kb) {
            __syncthreads();   // all waves done reading prev Ks/Vt
            // ---- commit staged K ----
            #pragma unroll
            for (int i = 0; i < 2; ++i) {
                int u = t + 256 * i, row = u >> 3, s = u & 7;
                *(bf16x8*)(&Ks[row * 64 + (s ^ (row & 7)) * 8]) = rk[i];
            }
            // ---- commit staged V transposed: Vt[d][k], k = lane ----
            #pragma unroll
            for (int c = 0; c < 2; ++c) {
                int d0 = (w * 2 + c) * 8;
                #pragma unroll
                for (int m = 0; m < 8; ++m) {
                    int d = d0 + m;
                    Vt[d * 64 + (((l >> 3) ^ (d & 7)) * 8) + (l & 7)] = rv[c][m];
                }
            }
            // ---- prefetch next K,V ----
            if (kb < qb) {
                int kn = (kb + 1) * 64;
                #pragma unroll
                for (int i = 0; i < 2; ++i) {
                    int u = t + 256 * i, row = u >> 3, s = u & 7;
                    rk[i] = *(const bf16x8*)(QKV + baseK + (size_t)(kn + row) * NQKV + s * 8);
                }
                #pragma unroll
                for (int c = 0; c < 2; ++c) {
                    int d0 = (w * 2 + c) * 8;
                    rv[c] = *(const bf16x8*)(QKV + baseV + (size_t)(kn + l) * NQKV + d0);
                }
            }
            __syncthreads();

            // ---- S = Q @ K^T ----
            f32x4 sf[4] = {};
            #pragma unroll
            for (int tt = 0; tt < 2; ++tt) {
                #pragma unroll
                for (int ni = 0; ni < 4; ++ni) {
                    int kc = ni * 16 + lr;
                    bf16x8 kf = *(const bf16x8*)(&Ks[kc * 64 + ((tt * 4 + lg) ^ (kc & 7)) * 8]);
                    sf[ni] = __builtin_amdgcn_mfma_f32_16x16x32_bf16(qf[tt], kf, sf[ni], 0, 0, 0);
                }
            }

            // ---- scale + causal mask (diag tile only) ----
            float z[4][4];
            #pragma unroll
            for (int ni = 0; ni < 4; ++ni) {
                #pragma unroll
                for (int r = 0; r < 4; ++r) {
                    float v = sf[ni][r] * SCL;
                    if (kb == qb && (ni * 16 + lr) > (w * 16 + lg * 4 + r))
                        v = -INFINITY;
                    z[ni][r] = v;
                }
            }

            // ---- online softmax (wave-parallel, 16-lane groups) ----
            #pragma unroll
            for (int r = 0; r < 4; ++r) {
                float rm = fmaxf(fmaxf(z[0][r], z[1][r]), fmaxf(z[2][r], z[3][r]));
                rm = fmaxf(rm, __shfl_xor(rm, 1));
                rm = fmaxf(rm, __shfl_xor(rm, 2));
                rm = fmaxf(rm, __shfl_xor(rm, 4));
                rm = fmaxf(rm, __shfl_xor(rm, 8));
                float mnew = fmaxf(m_i[r], rm);
                float corr = exp2f(m_i[r] - mnew);   // 0 on first tile
                float rs = 0.f;
                int qr = lg * 4 + r;
                #pragma unroll
                for (int ni = 0; ni < 4; ++ni) {
                    float p = exp2f(z[ni][r] - mnew);
                    rs += p;
                    int k = ni * 16 + lr;
                    Ps[w * 1024 + qr * 64 + (((k >> 3) ^ (qr & 7)) * 8) + (k & 7)] = f2bf(p);
                }
                rs += __shfl_xor(rs, 1);
                rs += __shfl_xor(rs, 2);
                rs += __shfl_xor(rs, 4);
                rs += __shfl_xor(rs, 8);
                l_i[r] = l_i[r] * corr + rs;
                m_i[r] = mnew;
                #pragma unroll
                for (int ni = 0; ni < 4; ++ni) o[ni][r] *= corr;
            }

            // ---- O += P @ V  (P from wave-private LDS, V^T swizzled) ----
            #pragma unroll
            for (int tt = 0; tt < 2; ++tt) {
                bf16x8 pf = *(const bf16x8*)(&Ps[w * 1024 + lr * 64 + ((tt * 4 + lg) ^ (lr & 7)) * 8]);
                #pragma unroll
                for (int ni = 0; ni < 4; ++ni) {
                    int d = ni * 16 + lr;
                    bf16x8 vf = *(const bf16x8*)(&Vt[d * 64 + ((tt * 4 + lg) ^ (d & 7)) * 8]);
                    o[ni] = __builtin_amdgcn_mfma_f32_16x16x32_bf16(pf, vf, o[ni], 0, 0, 0);
                }
            }
        }

        // ---- normalize + store bf16 ----
        #pragma unroll
        for (int r = 0; r < 4; ++r) {
            float inv = 1.0f / l_i[r];
            int q = q0 + w * 16 + lg * 4 + r;
            #pragma unroll
            for (int ni = 0; ni < 4; ++ni) {
                Aout[(size_t)(b * SEQ + q) * D_MODEL + h * 64 + ni * 16 + lr] =
                    f2bf(o[ni][r] * inv);
            }
        }
    }
}

// ---------------------------------------------------------------------------
extern "C" void kernel_launch(void* const* d_in, const int* in_sizes, int n_in,
                              void* d_out, int out_size, void* d_ws, size_t ws_size,
                              hipStream_t stream) {
    const float* x  = (const float*)d_in[0];
    const float* Wq = (const float*)d_in[1];
    const float* bq = (const float*)d_in[2];
    const float* Wk = (const float*)d_in[3];
    const float* bk = (const float*)d_in[4];
    const float* Wv = (const float*)d_in[5];
    const float* bv = (const float*)d_in[6];
    const float* Wo = (const float*)d_in[7];
    const float* bo = (const float*)d_in[8];
    float* out = (float*)d_out;

    // ws layout (shorts): xb[4096*1024] BtQKV[1536*1024] WoT[1024*1024]
    //                     QKV[4096*1536] Abuf[4096*1024] | bcat fp32[1536]
    short* xb    = (short*)d_ws;
    short* BtQKV = xb    + (size_t)MROWS * D_MODEL;
    short* WoT   = BtQKV + (size_t)NQKV * 1024;
    short* QKV   = WoT   + (size_t)1024 * 1024;
    short* Abuf  = QKV   + (size_t)MROWS * NQKV;
    float* bcat  = (float*)(Abuf + (size_t)MROWS * D_MODEL);

    dim3 blk(256);
    // x -> bf16
    convert_bf16_kernel<<<dim3(MROWS * D_MODEL / 4 / 256), blk, 0, stream>>>(
        x, xb, MROWS * D_MODEL / 4);
    // W^T conversions into packed QKV weight + Wo
    transpose_w_kernel<<<dim3(16, 16), blk, 0, stream>>>(Wq, 1024, BtQKV);
    transpose_w_kernel<<<dim3(4, 16),  blk, 0, stream>>>(Wk, 256,  BtQKV + (size_t)1024 * 1024);
    transpose_w_kernel<<<dim3(4, 16),  blk, 0, stream>>>(Wv, 256,  BtQKV + (size_t)1280 * 1024);
    transpose_w_kernel<<<dim3(16, 16), blk, 0, stream>>>(Wo, 1024, WoT);
    bias_concat_kernel<<<dim3(6), blk, 0, stream>>>(bq, bk, bv, bcat);
    // fused QKV projection: [4096,1536] = xb @ BtQKV^T
    gemm_kernel<true><<<dim3(NQKV / 128, MROWS / 128), blk, 0, stream>>>(
        xb, BtQKV, bcat, QKV, NQKV);
    // attention (paired q-tiles: grid.x = 16 covers 32 q-tiles)
    attn_kernel<<<dim3(16, N_HEADS, BATCH), blk, 0, stream>>>(QKV, Abuf);
    // output projection: out fp32 = Abuf @ WoT^T + bo
    gemm_kernel<false><<<dim3(D_MODEL / 128, MROWS / 128), blk, 0, stream>>>(
        Abuf, WoT, bo, out, D_MODEL);
}